// Round 8
// baseline (363.857 us; speedup 1.0000x reference)
//
#include <hip/hip_runtime.h>
#include <math.h>

// ---------------------------------------------------------------------------
// N=32768 nodes, E=524288 edges, node feat 64, edge feat 32, H=4 x C=64 = 256.
// MFMA fragment maps (mfma_f32_16x16x32_f16):
//   A(16x32): lane l, reg j -> row=l&15,  k=(l>>4)*8+j
//   B(32x16): lane l, reg j -> col=l&15,  k=(l>>4)*8+j   (store W^T[col][k])
//   C/D:      lane l, reg r -> col=l&15,  row=(l>>4)*4+r
// TransformerConv decomposition (softmax cancels per-(n,h) constants):
//   logit = Y[n]·x2[s] + (0.125 Wk_h bq_h)·x2[s] + qtp[n]·ea   (Y = 0.125 x2·WqWk^T)
//   msg   = (Σw x2[s])@Wv_h + l·bv + (Σw ea)@We3_h             (k_tpost, K=96 MFMA)
// Edge-linear producer (k_emm2): GATHERS ea[perm[j]] (random L3 reads) and
// writes e1p/e2p/eap sequentially — no random writes anywhere (R7 lesson:
// random 64B-granule writes ran at 30% peak with RMW fetch overhead).
// ---------------------------------------------------------------------------

typedef __attribute__((ext_vector_type(2))) _Float16 half2v;
typedef __attribute__((ext_vector_type(4))) _Float16 half4v;
typedef __attribute__((ext_vector_type(8))) _Float16 half8v;
typedef __attribute__((ext_vector_type(4))) float float4v;

// ---------------- edge_index dtype detection + convert(+hist) --------------
__global__ void k_detect(const unsigned int* __restrict__ w, int* __restrict__ flag)
{
    __shared__ int any;
    if (threadIdx.x == 0) any = 0;
    __syncthreads();
    int found = 0;
    for (int i = threadIdx.x; i < 2048; i += 256)
        if (w[2 * i + 1] != 0u) found = 1;
    if (found) atomicOr(&any, 1);
    __syncthreads();
    if (threadIdx.x == 0) flag[0] = any ? 0 : 1;   // 1 => int64
}

__global__ void k_cvt(const void* __restrict__ eidx, const int* __restrict__ flag,
                      int* __restrict__ out, int* __restrict__ counts, int E)
{
    int i = blockIdx.x * blockDim.x + threadIdx.x;
    if (i >= 2 * E) return;
    int v = flag[0] ? (int)((const long long*)eidx)[i] : ((const int*)eidx)[i];
    out[i] = v;
    if (i >= E) atomicAdd(&counts[v], 1);    // dst histogram fused
}

// ---------------- CSR build ------------------------------------------------
__global__ void k_scan(const int* __restrict__ counts, int* __restrict__ offs,
                       int* __restrict__ cursor, int N)
{
    __shared__ int part[1024];
    int t = threadIdx.x;
    int base = t * 32;
    int loc[32];
    int s = 0;
#pragma unroll
    for (int i = 0; i < 32; i++) { loc[i] = counts[base + i]; s += loc[i]; }
    part[t] = s;
    __syncthreads();
    for (int off = 1; off < 1024; off <<= 1) {
        int v = (t >= off) ? part[t - off] : 0;
        __syncthreads();
        part[t] += v;
        __syncthreads();
    }
    int run = part[t] - s;
#pragma unroll
    for (int i = 0; i < 32; i++) {
        offs[base + i] = run;
        cursor[base + i] = run;
        run += loc[i];
    }
    if (t == 1023) offs[N] = run;
}

// pure scatter (no payload): perm/sperm only
__global__ void k_scatter(const int* __restrict__ dst, const int* __restrict__ srcA,
                          int* __restrict__ cursor, int* __restrict__ perm,
                          int* __restrict__ sperm, int E)
{
    int i = blockIdx.x * blockDim.x + threadIdx.x;
    if (i >= E) return;
    int d = dst[i];
    int p = atomicAdd(&cursor[d], 1);
    perm[p] = i;
    sperm[p] = srcA[i];
}

// ---------------- edge-linear via MFMA, gather-read form -------------------
// wave = 16 edges; lane reads ea[perm[jb+cr]] row-slice (32B), cvt fp16 in-reg.
// Writes epA (+epB) and optionally eap — all sequential.
template<int WEAP, int DUAL>
__global__ __launch_bounds__(256) void k_emm2(
    const float* __restrict__ ea, const int* __restrict__ perm,
    const _Float16* __restrict__ WtA, const float* __restrict__ beA,
    _Float16* __restrict__ epA,
    const _Float16* __restrict__ WtB, const float* __restrict__ beB,
    _Float16* __restrict__ epB,
    _Float16* __restrict__ eap)
{
    int t = threadIdx.x;
    int wid = t >> 6, l = t & 63;
    int jb = (blockIdx.x * 4 + wid) * 16;
    int cr = l & 15, kg = l >> 4;
    int e = perm[jb + cr];
    const float* ar = ea + (size_t)e * 32 + kg * 8;
    float4 f0 = *(const float4*)ar;
    float4 f1 = *(const float4*)(ar + 4);
    half8v a;
    a[0] = (_Float16)f0.x; a[1] = (_Float16)f0.y;
    a[2] = (_Float16)f0.z; a[3] = (_Float16)f0.w;
    a[4] = (_Float16)f1.x; a[5] = (_Float16)f1.y;
    a[6] = (_Float16)f1.z; a[7] = (_Float16)f1.w;
    if (WEAP)
        *(half8v*)&eap[(size_t)(jb + cr) * 32 + kg * 8] = a;
    int orow = kg * 4;
#pragma unroll
    for (int c = 0; c < 4; c++) {
        half8v b = *(const half8v*)&WtA[(size_t)(c * 16 + cr) * 32 + kg * 8];
        float4v d = __builtin_amdgcn_mfma_f32_16x16x32_f16(a, b, (float4v){0.f,0.f,0.f,0.f}, 0, 0, 0);
        int col = c * 16 + cr;
        float bv = beA ? beA[col] : 0.f;
#pragma unroll
        for (int r = 0; r < 4; r++)
            epA[(size_t)(jb + orow + r) * 64 + col] = (_Float16)(d[r] + bv);
    }
    if (DUAL) {
#pragma unroll
        for (int c = 0; c < 4; c++) {
            half8v b = *(const half8v*)&WtB[(size_t)(c * 16 + cr) * 32 + kg * 8];
            float4v d = __builtin_amdgcn_mfma_f32_16x16x32_f16(a, b, (float4v){0.f,0.f,0.f,0.f}, 0, 0, 0);
            int col = c * 16 + cr;
            float bv = beB ? beB[col] : 0.f;
#pragma unroll
            for (int r = 0; r < 4; r++)
                epB[(size_t)(jb + orow + r) * 64 + col] = (_Float16)(d[r] + bv);
        }
    }
}

// ---------------- edge-linear via MFMA from sequential eap -----------------
__global__ __launch_bounds__(256) void k_emm(
    const _Float16* __restrict__ eap,
    const _Float16* __restrict__ WtA, const float* __restrict__ beA,
    _Float16* __restrict__ epA)
{
    int t = threadIdx.x;
    int wid = t >> 6, l = t & 63;
    int jb = (blockIdx.x * 4 + wid) * 16;
    int cr = l & 15, kg = l >> 4;
    half8v a = *(const half8v*)&eap[(size_t)(jb + cr) * 32 + kg * 8];
    int orow = kg * 4;
#pragma unroll
    for (int c = 0; c < 4; c++) {
        half8v b = *(const half8v*)&WtA[(size_t)(c * 16 + cr) * 32 + kg * 8];
        float4v d = __builtin_amdgcn_mfma_f32_16x16x32_f16(a, b, (float4v){0.f,0.f,0.f,0.f}, 0, 0, 0);
        int col = c * 16 + cr;
        float bv = beA ? beA[col] : 0.f;
#pragma unroll
        for (int r = 0; r < 4; r++)
            epA[(size_t)(jb + orow + r) * 64 + col] = (_Float16)(d[r] + bv);
    }
}

// ---------------- weight prep ----------------------------------------------
__global__ __launch_bounds__(256) void k_prep(
    const float* __restrict__ x, int NX,
    const float* __restrict__ wq, const float* __restrict__ wk,
    const float* __restrict__ wv, const float* __restrict__ wskip,
    const float* __restrict__ wl, const float* __restrict__ wr,
    const float* __restrict__ w1a, const float* __restrict__ w1b,
    const float* __restrict__ w2a, const float* __restrict__ w2b,
    const float* __restrict__ we3, const float* __restrict__ bq,
    const float* __restrict__ we1, const float* __restrict__ we2,
    const float* __restrict__ we4,
    _Float16* __restrict__ xh,
    _Float16* __restrict__ Wts, _Float16* __restrict__ Gt,
    _Float16* __restrict__ Wtl, _Float16* __restrict__ Wtr,
    _Float16* __restrict__ Wt1a, _Float16* __restrict__ Wt1b,
    _Float16* __restrict__ Wt2a, _Float16* __restrict__ Wt2b,
    _Float16* __restrict__ Mt, float* __restrict__ cst,
    _Float16* __restrict__ Wt1e, _Float16* __restrict__ Wt2e,
    _Float16* __restrict__ Wt4e, float* __restrict__ zt,
    _Float16* __restrict__ Bt3)
{
    int g = blockIdx.x * 256 + threadIdx.x;
    if (g < 16384) {                       // Wts[c<256][k<64]
        int c = g >> 6, k = g & 63;
        Wts[g] = (_Float16)wskip[(size_t)k * 256 + c];
    } else if (g < 32768) {                // Gt[col<256][d<64] = 0.125 WqWk^T
        int q = g - 16384, col = q >> 6, d = q & 63;
        int h = col >> 6, c = col & 63;
        float s = 0.f;
        for (int mq = 0; mq < 64; mq++)
            s = fmaf(wq[(size_t)d * 256 + h * 64 + mq],
                     wk[(size_t)c * 256 + h * 64 + mq], s);
        Gt[q] = (_Float16)(0.125f * s);
    } else if (g < 49152) {                // wl/wr: Wt[c<64][k<256]
        int q = g - 32768, c = q >> 8, k = q & 255;
        Wtl[q] = (_Float16)wl[(size_t)k * 64 + c];
        Wtr[q] = (_Float16)wr[(size_t)k * 64 + c];
    } else if (g < 53248) {                // w1a/w1b 64x64
        int q = g - 49152, m = q >> 6, k = q & 63;
        Wt1a[q] = (_Float16)w1a[(size_t)k * 64 + m];
        Wt1b[q] = (_Float16)w1b[(size_t)k * 64 + m];
    } else if (g < 55296) {                // w2a -> Wt2a[m<32][k<64]
        int q = g - 53248, m = q >> 6, k = q & 63;
        Wt2a[q] = (_Float16)w2a[(size_t)k * 32 + m];
    } else if (g < 57344) {                // w2b -> Wt2b[c<64][k<31]
        int q = g - 55296, c = q >> 5, k = q & 31;
        Wt2b[q] = (_Float16)w2b[(size_t)k * 64 + c];
    } else if (g < 65536) {                // Mt[m<128][d<64]
        int q = g - 57344, m = q >> 6, d = q & 63;
        int h = m >> 5, kk = m & 31;
        float s = 0.f;
        for (int c = 0; c < 64; c++)
            s = fmaf(wq[(size_t)d * 256 + h * 64 + c],
                     we3[(size_t)kk * 256 + h * 64 + c], s);
        Mt[q] = (_Float16)(0.125f * s);
    } else if (g < 65664) {                // cst[128]
        int m = g - 65536, h = m >> 5, kk = m & 31;
        float s = 0.f;
        for (int c = 0; c < 64; c++)
            s = fmaf(bq[h * 64 + c], we3[(size_t)kk * 256 + h * 64 + c], s);
        cst[m] = 0.125f * s;
    } else if (g < 67712) {                // Wt1e[c<64][k<32]
        int q = g - 65664, c = q >> 5, k = q & 31;
        Wt1e[q] = (_Float16)we1[(size_t)k * 64 + c];
    } else if (g < 69760) {
        int q = g - 67712, c = q >> 5, k = q & 31;
        Wt2e[q] = (_Float16)we2[(size_t)k * 64 + c];
    } else if (g < 71808) {
        int q = g - 69760, c = q >> 5, k = q & 31;
        Wt4e[q] = (_Float16)we4[(size_t)k * 64 + c];
    } else if (g < 72064) {                // zt[h*64+c] = 0.125 Wk_h^T bq_h
        int q = g - 71808, h = q >> 6, c = q & 63;
        float s = 0.f;
        for (int mq = 0; mq < 64; mq++)
            s = fmaf(wk[(size_t)c * 256 + h * 64 + mq], bq[h * 64 + mq], s);
        zt[q] = 0.125f * s;
    } else if (g < 96640) {                // Bt3[(h*64+col)*96 + k]
        int q = g - 72064;
        int hc = q / 96, k = q - hc * 96;
        int h = hc >> 6, col = hc & 63;
        float v = (k < 64) ? wv[(size_t)k * 256 + h * 64 + col]
                           : we3[(size_t)(k - 64) * 256 + h * 64 + col];
        Bt3[q] = (_Float16)v;
    }
    for (int i = g; i < NX; i += 512 * 256)
        xh[i] = (_Float16)x[i];
}

// ---------------- fused 2-layer MLP via MFMA -------------------------------
template<int MID>
__global__ __launch_bounds__(256) void k_mlp(
    const _Float16* __restrict__ A,
    const _Float16* __restrict__ Wt1, const float* __restrict__ b1,
    const _Float16* __restrict__ Wt2, const float* __restrict__ b2,
    _Float16* __restrict__ out)
{
    __shared__ _Float16 As[64][72];
    __shared__ _Float16 Ws1[MID][72];
    __shared__ _Float16 Ws2[64][MID + 8];
    __shared__ _Float16 mids[64][MID + 8];
    int t = threadIdx.x;
    int n0 = blockIdx.x * 64;
    for (int f = t; f < 512; f += 256) {
        int r = f >> 3, seg = f & 7;
        *(uint4*)&As[r][seg * 8] = *(const uint4*)&A[(size_t)(n0 + r) * 64 + seg * 8];
    }
    for (int f = t; f < MID * 8; f += 256) {
        int r = f >> 3, seg = f & 7;
        *(uint4*)&Ws1[r][seg * 8] = *(const uint4*)&Wt1[(size_t)r * 64 + seg * 8];
    }
    constexpr int CH = MID / 8;
    for (int f = t; f < 64 * CH; f += 256) {
        int r = f / CH, seg = f % CH;
        *(uint4*)&Ws2[r][seg * 8] = *(const uint4*)&Wt2[(size_t)r * MID + seg * 8];
    }
    __syncthreads();
    int w = t >> 6, l = t & 63;
    int arow = w * 16 + (l & 15);
    int kg = (l >> 4) * 8;
    int colg = l & 15;
    int orow = w * 16 + (l >> 4) * 4;
    half8v a0 = *(const half8v*)&As[arow][kg];
    half8v a1 = *(const half8v*)&As[arow][32 + kg];
    constexpr int NCT1 = MID / 16;
#pragma unroll
    for (int ct = 0; ct < NCT1; ct++) {
        half8v b0 = *(const half8v*)&Ws1[ct * 16 + colg][kg];
        half8v b1v = *(const half8v*)&Ws1[ct * 16 + colg][32 + kg];
        float4v acc = {0.f, 0.f, 0.f, 0.f};
        acc = __builtin_amdgcn_mfma_f32_16x16x32_f16(a0, b0, acc, 0, 0, 0);
        acc = __builtin_amdgcn_mfma_f32_16x16x32_f16(a1, b1v, acc, 0, 0, 0);
        int col = ct * 16 + colg;
        float bb = b1[col];
#pragma unroll
        for (int r = 0; r < 4; r++)
            mids[orow + r][col] = (_Float16)fmaxf(acc[r] + bb, 0.f);
    }
    __syncthreads();
    half8v m0 = *(const half8v*)&mids[arow][kg];
#pragma unroll
    for (int ct = 0; ct < 4; ct++) {
        half8v b0 = *(const half8v*)&Ws2[ct * 16 + colg][kg];
        float4v acc = {0.f, 0.f, 0.f, 0.f};
        acc = __builtin_amdgcn_mfma_f32_16x16x32_f16(m0, b0, acc, 0, 0, 0);
        if (MID == 64) {
            half8v m1 = *(const half8v*)&mids[arow][32 + kg];
            half8v b1v = *(const half8v*)&Ws2[ct * 16 + colg][32 + kg];
            acc = __builtin_amdgcn_mfma_f32_16x16x32_f16(m1, b1v, acc, 0, 0, 0);
        }
        int col = ct * 16 + colg;
        float bb = b2[col];
#pragma unroll
        for (int r = 0; r < 4; r++)
            out[(size_t)(n0 + orow + r) * 64 + col] = (_Float16)(acc[r] + bb);
    }
}

// ---------------- fused Y/skip/qt projections via MFMA ---------------------
// grid (N/64, 9): y<4 -> Y tile; y<8 -> skip tile; y==8 -> qt.
__global__ __launch_bounds__(256) void k_gemm4m(
    const _Float16* __restrict__ A,
    const _Float16* __restrict__ Gt,
    const _Float16* __restrict__ Wts, const float* __restrict__ bs,
    const _Float16* __restrict__ Mt,  const float* __restrict__ cst,
    _Float16* __restrict__ Yb, _Float16* __restrict__ skiph,
    _Float16* __restrict__ qtp)
{
    __shared__ _Float16 As[64][72];
    __shared__ _Float16 Ws[128][72];
    int t = threadIdx.x;
    int n0 = blockIdx.x * 64;
    int y = blockIdx.y;
    for (int f = t; f < 512; f += 256) {
        int r = f >> 3, seg = f & 7;
        *(uint4*)&As[r][seg * 8] = *(const uint4*)&A[(size_t)(n0 + r) * 64 + seg * 8];
    }
    if (y < 8) {
        int j0 = (y & 3) * 64;
        const _Float16* Wt = (y < 4) ? Gt : Wts;
        for (int f = t; f < 512; f += 256) {
            int c = f >> 3, seg = f & 7;
            *(uint4*)&Ws[c][seg * 8] = *(const uint4*)&Wt[(size_t)(j0 + c) * 64 + seg * 8];
        }
    } else {
        for (int f = t; f < 1024; f += 256) {
            int c = f >> 3, seg = f & 7;
            *(uint4*)&Ws[c][seg * 8] = *(const uint4*)&Mt[(size_t)c * 64 + seg * 8];
        }
    }
    __syncthreads();
    int w = t >> 6, l = t & 63;
    int arow = w * 16 + (l & 15);
    int kg = (l >> 4) * 8;
    int colg = l & 15;
    int orow = w * 16 + (l >> 4) * 4;
    half8v a0 = *(const half8v*)&As[arow][kg];
    half8v a1 = *(const half8v*)&As[arow][32 + kg];
    if (y < 8) {
        int j0 = (y & 3) * 64;
        _Float16* O = (y < 4) ? Yb : skiph;
#pragma unroll
        for (int ct = 0; ct < 4; ct++) {
            half8v b0 = *(const half8v*)&Ws[ct * 16 + colg][kg];
            half8v b1 = *(const half8v*)&Ws[ct * 16 + colg][32 + kg];
            float4v a = {0.f, 0.f, 0.f, 0.f};
            a = __builtin_amdgcn_mfma_f32_16x16x32_f16(a0, b0, a, 0, 0, 0);
            a = __builtin_amdgcn_mfma_f32_16x16x32_f16(a1, b1, a, 0, 0, 0);
            int col = j0 + ct * 16 + colg;
            float bb = (y < 4) ? 0.f : bs[col];
#pragma unroll
            for (int r = 0; r < 4; r++)
                O[(size_t)(n0 + orow + r) * 256 + col] = (_Float16)(a[r] + bb);
        }
    } else {
#pragma unroll
        for (int ct = 0; ct < 8; ct++) {
            half8v b0 = *(const half8v*)&Ws[ct * 16 + colg][kg];
            half8v b1 = *(const half8v*)&Ws[ct * 16 + colg][32 + kg];
            float4v a = {0.f, 0.f, 0.f, 0.f};
            a = __builtin_amdgcn_mfma_f32_16x16x32_f16(a0, b0, a, 0, 0, 0);
            a = __builtin_amdgcn_mfma_f32_16x16x32_f16(a1, b1, a, 0, 0, 0);
            int col = ct * 16 + colg;
            float bb = cst[col];
#pragma unroll
            for (int r = 0; r < 4; r++)
                qtp[(size_t)(n0 + orow + r) * 128 + col] = (_Float16)(a[r] + bb);
        }
    }
}

// ---------------- GINE aggregation, quad layout ----------------------------
__global__ __launch_bounds__(256) void k_gine2(
    const _Float16* __restrict__ xin, const _Float16* __restrict__ ep,
    const float* __restrict__ epsp,
    const int* __restrict__ offs, const int* __restrict__ sperm,
    _Float16* __restrict__ hout)
{
    int t = threadIdx.x;
    int wid  = __builtin_amdgcn_readfirstlane(t >> 6);
    int n    = blockIdx.x * 4 + wid;
    int lane = t & 63;
    int g = lane >> 4, li = lane & 15, c0 = li * 4;
    int j0 = __builtin_amdgcn_readfirstlane(offs[n]);
    int j1 = __builtin_amdgcn_readfirstlane(offs[n + 1]);
    float4 acc = {0.f, 0.f, 0.f, 0.f};
    for (int jq = j0; jq < j1; jq += 4) {
        int j = jq + g;
        int jc = (j < j1) ? j : (j1 - 1);
        int s = sperm[jc];
        half4v ev = *(const half4v*)&ep[(size_t)jc * 64 + c0];
        half4v xv = *(const half4v*)&xin[(size_t)s * 64 + c0];
        if (j < j1) {
            acc.x += fmaxf((float)xv[0] + (float)ev[0], 0.f);
            acc.y += fmaxf((float)xv[1] + (float)ev[1], 0.f);
            acc.z += fmaxf((float)xv[2] + (float)ev[2], 0.f);
            acc.w += fmaxf((float)xv[3] + (float)ev[3], 0.f);
        }
    }
    acc.x += __shfl_xor(acc.x, 16); acc.x += __shfl_xor(acc.x, 32);
    acc.y += __shfl_xor(acc.y, 16); acc.y += __shfl_xor(acc.y, 32);
    acc.z += __shfl_xor(acc.z, 16); acc.z += __shfl_xor(acc.z, 32);
    acc.w += __shfl_xor(acc.w, 16); acc.w += __shfl_xor(acc.w, 32);
    if (g == 0) {
        float eps1 = 1.f + epsp[0];
        half4v xn = *(const half4v*)&xin[(size_t)n * 64 + c0];
        half4v o;
        o[0] = (_Float16)(eps1 * (float)xn[0] + acc.x);
        o[1] = (_Float16)(eps1 * (float)xn[1] + acc.y);
        o[2] = (_Float16)(eps1 * (float)xn[2] + acc.z);
        o[3] = (_Float16)(eps1 * (float)xn[3] + acc.w);
        *(half4v*)&hout[(size_t)n * 64 + c0] = o;
    }
}

// ---------------- TransformerConv core: x2-gather only ---------------------
// wave = node; lane = h*16 + c; lane covers x2 channels [c*4, c*4+4).
template<int USE_EAP>
__global__ __launch_bounds__(256) void k_tconv5(
    const _Float16* __restrict__ Yb, const _Float16* __restrict__ qtp,
    const float* __restrict__ zt, const _Float16* __restrict__ x2h,
    const _Float16* __restrict__ eap, const float* __restrict__ ea,
    const int* __restrict__ perm, const int* __restrict__ offs,
    const int* __restrict__ sperm,
    _Float16* __restrict__ xaccb, _Float16* __restrict__ wab,
    float* __restrict__ lb)
{
    int t = threadIdx.x;
    int wid = __builtin_amdgcn_readfirstlane(t >> 6);
    int n = blockIdx.x * 4 + wid;
    int lane = t & 63;
    int h = lane >> 4, c = lane & 15;
    float yb0, yb1, yb2, yb3;
    {
        half4v Y4 = *(const half4v*)&Yb[(size_t)n * 256 + h * 64 + c * 4];
        float4 z4 = *(const float4*)&zt[h * 64 + c * 4];
        yb0 = (float)Y4[0] + z4.x; yb1 = (float)Y4[1] + z4.y;
        yb2 = (float)Y4[2] + z4.z; yb3 = (float)Y4[3] + z4.w;
    }
    half2v qt2 = *(const half2v*)&qtp[(size_t)n * 128 + h * 32 + c * 2];
    float qt0 = (float)qt2[0], qt1 = (float)qt2[1];
    int j0 = __builtin_amdgcn_readfirstlane(offs[n]);
    int j1 = __builtin_amdgcn_readfirstlane(offs[n + 1]);
    float l = 0.f;
    float xa0 = 0.f, xa1 = 0.f, xa2 = 0.f, xa3 = 0.f;
    float wa0 = 0.f, wa1 = 0.f;
    int j = j0;
    for (; j + 1 < j1; j += 2) {
        int s0 = __builtin_amdgcn_readfirstlane(sperm[j]);
        int s1 = __builtin_amdgcn_readfirstlane(sperm[j + 1]);
        half4v xA = *(const half4v*)&x2h[(size_t)s0 * 64 + c * 4];
        half4v xB = *(const half4v*)&x2h[(size_t)s1 * 64 + c * 4];
        float eA0, eA1, eB0, eB1;
        if (USE_EAP) {
            half2v vA = *(const half2v*)&eap[(size_t)j * 32 + c * 2];
            half2v vB = *(const half2v*)&eap[(size_t)(j + 1) * 32 + c * 2];
            eA0 = (float)vA[0]; eA1 = (float)vA[1];
            eB0 = (float)vB[0]; eB1 = (float)vB[1];
        } else {
            int e0 = __builtin_amdgcn_readfirstlane(perm[j]);
            int e1 = __builtin_amdgcn_readfirstlane(perm[j + 1]);
            float2 fA = *(const float2*)&ea[(size_t)e0 * 32 + c * 2];
            float2 fB = *(const float2*)&ea[(size_t)e1 * 32 + c * 2];
            eA0 = fA.x; eA1 = fA.y; eB0 = fB.x; eB1 = fB.y;
        }
        float xA0 = (float)xA[0], xA1f = (float)xA[1];
        float xA2 = (float)xA[2], xA3 = (float)xA[3];
        float xB0 = (float)xB[0], xB1f = (float)xB[1];
        float xB2 = (float)xB[2], xB3 = (float)xB[3];
        float p0 = yb0 * xA0 + yb1 * xA1f + yb2 * xA2 + yb3 * xA3
                 + qt0 * eA0 + qt1 * eA1;
        float p1 = yb0 * xB0 + yb1 * xB1f + yb2 * xB2 + yb3 * xB3
                 + qt0 * eB0 + qt1 * eB1;
        p0 += __shfl_xor(p0, 1); p1 += __shfl_xor(p1, 1);
        p0 += __shfl_xor(p0, 2); p1 += __shfl_xor(p1, 2);
        p0 += __shfl_xor(p0, 4); p1 += __shfl_xor(p1, 4);
        p0 += __shfl_xor(p0, 8); p1 += __shfl_xor(p1, 8);
        float w0 = __expf(p0), w1 = __expf(p1);   // logits O(0.5): no-max exact
        l += w0 + w1;
        xa0 += w0 * xA0 + w1 * xB0;
        xa1 += w0 * xA1f + w1 * xB1f;
        xa2 += w0 * xA2 + w1 * xB2;
        xa3 += w0 * xA3 + w1 * xB3;
        wa0 += w0 * eA0 + w1 * eB0;
        wa1 += w0 * eA1 + w1 * eB1;
    }
    if (j < j1) {
        int s0 = __builtin_amdgcn_readfirstlane(sperm[j]);
        half4v xA = *(const half4v*)&x2h[(size_t)s0 * 64 + c * 4];
        float eA0, eA1;
        if (USE_EAP) {
            half2v vA = *(const half2v*)&eap[(size_t)j * 32 + c * 2];
            eA0 = (float)vA[0]; eA1 = (float)vA[1];
        } else {
            int e0 = __builtin_amdgcn_readfirstlane(perm[j]);
            float2 fA = *(const float2*)&ea[(size_t)e0 * 32 + c * 2];
            eA0 = fA.x; eA1 = fA.y;
        }
        float xA0 = (float)xA[0], xA1f = (float)xA[1];
        float xA2 = (float)xA[2], xA3 = (float)xA[3];
        float p0 = yb0 * xA0 + yb1 * xA1f + yb2 * xA2 + yb3 * xA3
                 + qt0 * eA0 + qt1 * eA1;
        p0 += __shfl_xor(p0, 1); p0 += __shfl_xor(p0, 2);
        p0 += __shfl_xor(p0, 4); p0 += __shfl_xor(p0, 8);
        float w0 = __expf(p0);
        l += w0;
        xa0 += w0 * xA0; xa1 += w0 * xA1f; xa2 += w0 * xA2; xa3 += w0 * xA3;
        wa0 += w0 * eA0; wa1 += w0 * eA1;
    }
    half4v xo;
    xo[0] = (_Float16)xa0; xo[1] = (_Float16)xa1;
    xo[2] = (_Float16)xa2; xo[3] = (_Float16)xa3;
    *(half4v*)&xaccb[(size_t)n * 256 + h * 64 + c * 4] = xo;
    half2v wo;
    wo[0] = (_Float16)wa0; wo[1] = (_Float16)wa1;
    *(half2v*)&wab[(size_t)n * 128 + h * 32 + c * 2] = wo;
    if (c == 0) lb[n * 4 + h] = l;
}

// ---------------- tconv epilogue: out = ([xacc|wa]@[Wv;We3])/l + bv + skip -
__global__ __launch_bounds__(256) void k_tpost(
    const _Float16* __restrict__ xaccb, const _Float16* __restrict__ wab,
    const float* __restrict__ lb, const _Float16* __restrict__ Bt3,
    const float* __restrict__ bv, _Float16* __restrict__ skiph)
{
    int t = threadIdx.x;
    int h = t >> 6;
    int l = t & 63;
    int n0 = blockIdx.x * 64;
    int colg = l & 15, kg = (l >> 4) * 8;
    half8v Bf[4][3];
#pragma unroll
    for (int ct = 0; ct < 4; ct++) {
        size_t cb = (size_t)(h * 64 + ct * 16 + colg) * 96;
        Bf[ct][0] = *(const half8v*)&Bt3[cb + kg];
        Bf[ct][1] = *(const half8v*)&Bt3[cb + 32 + kg];
        Bf[ct][2] = *(const half8v*)&Bt3[cb + 64 + kg];
    }
#pragma unroll
    for (int rt = 0; rt < 4; rt++) {
        int arow = n0 + rt * 16 + (l & 15);
        half8v A0 = *(const half8v*)&xaccb[(size_t)arow * 256 + h * 64 + kg];
        half8v A1 = *(const half8v*)&xaccb[(size_t)arow * 256 + h * 64 + 32 + kg];
        half8v A2 = *(const half8v*)&wab[(size_t)arow * 128 + h * 32 + kg];
#pragma unroll
        for (int ct = 0; ct < 4; ct++) {
            float4v acc = {0.f, 0.f, 0.f, 0.f};
            acc = __builtin_amdgcn_mfma_f32_16x16x32_f16(A0, Bf[ct][0], acc, 0, 0, 0);
            acc = __builtin_amdgcn_mfma_f32_16x16x32_f16(A1, Bf[ct][1], acc, 0, 0, 0);
            acc = __builtin_amdgcn_mfma_f32_16x16x32_f16(A2, Bf[ct][2], acc, 0, 0, 0);
            int col = h * 64 + ct * 16 + colg;
            float bvc = bv[col];
#pragma unroll
            for (int r = 0; r < 4; r++) {
                int row = n0 + rt * 16 + (l >> 4) * 4 + r;
                float lv = lb[row * 4 + h];
                float rl = (lv > 0.f) ? 1.f / lv : 0.f;
                float bterm = (lv > 0.f) ? bvc : 0.f;
                size_t o = (size_t)row * 256 + col;
                float out = acc[r] * rl + bterm + (float)skiph[o];
                skiph[o] = (_Float16)out;
            }
        }
    }
}

// ---------------- GAT xl/xr projections (fused L+R, fp16 A) ----------------
__global__ __launch_bounds__(256) void k_gatgemm(
    const _Float16* __restrict__ A,
    const _Float16* __restrict__ WtL, const float* __restrict__ bL,
    const _Float16* __restrict__ WtR, const float* __restrict__ bR,
    _Float16* __restrict__ xlh, _Float16* __restrict__ xrh)
{
    __shared__ _Float16 As[64][136];
    __shared__ _Float16 WsL[64][136];
    __shared__ _Float16 WsR[64][136];
    int t = threadIdx.x;
    int n0 = blockIdx.x * 64;
    int w = t >> 6, l = t & 63;
    int arow = w * 16 + (l & 15);
    int kg = (l >> 4) * 8;
    int colg = l & 15;
    int orow = w * 16 + (l >> 4) * 4;
    float4v accL[4] = {{0.f,0.f,0.f,0.f},{0.f,0.f,0.f,0.f},
                       {0.f,0.f,0.f,0.f},{0.f,0.f,0.f,0.f}};
    float4v accR[4] = {{0.f,0.f,0.f,0.f},{0.f,0.f,0.f,0.f},
                       {0.f,0.f,0.f,0.f},{0.f,0.f,0.f,0.f}};
    for (int kh = 0; kh < 2; kh++) {
        __syncthreads();
        for (int f = t; f < 1024; f += 256) {
            int r = f >> 4, seg = f & 15;
            *(uint4*)&As[r][seg * 8] =
                *(const uint4*)&A[(size_t)(n0 + r) * 256 + kh * 128 + seg * 8];
            *(uint4*)&WsL[r][seg * 8] =
                *(const uint4*)&WtL[(size_t)r * 256 + kh * 128 + seg * 8];
            *(uint4*)&WsR[r][seg * 8] =
                *(const uint4*)&WtR[(size_t)r * 256 + kh * 128 + seg * 8];
        }
        __syncthreads();
#pragma unroll
        for (int ks = 0; ks < 4; ks++) {
            half8v a = *(const half8v*)&As[arow][ks * 32 + kg];
#pragma unroll
            for (int ct = 0; ct < 4; ct++) {
                half8v bl_ = *(const half8v*)&WsL[ct * 16 + colg][ks * 32 + kg];
                half8v br_ = *(const half8v*)&WsR[ct * 16 + colg][ks * 32 + kg];
                accL[ct] = __builtin_amdgcn_mfma_f32_16x16x32_f16(a, bl_, accL[ct], 0, 0, 0);
                accR[ct] = __builtin_amdgcn_mfma_f32_16x16x32_f16(a, br_, accR[ct], 0, 0, 0);
            }
        }
    }
#pragma unroll
    for (int ct = 0; ct < 4; ct++) {
        int col = ct * 16 + colg;
        float bvL = bL[col], bvR = bR[col];
#pragma unroll
        for (int r = 0; r < 4; r++) {
            xlh[(size_t)(n0 + orow + r) * 64 + col] = (_Float16)(accL[ct][r] + bvL);
            xrh[(size_t)(n0 + orow + r) * 64 + col] = (_Float16)(accR[ct][r] + bvR);
        }
    }
}

// ---------------- GATv2 aggregation, quad layout ---------------------------
__global__ __launch_bounds__(256) void k_gat2(
    const _Float16* __restrict__ xl, const _Float16* __restrict__ xr,
    const _Float16* __restrict__ e4p,
    const float* __restrict__ attv, const float* __restrict__ bias4,
    const int* __restrict__ offs, const int* __restrict__ sperm,
    float* __restrict__ out)
{
    int t = threadIdx.x;
    int wid  = __builtin_amdgcn_readfirstlane(t >> 6);
    int n    = blockIdx.x * 4 + wid;
    int lane = t & 63;
    int g = lane >> 4, li = lane & 15, c0 = li * 4;
    half4v xrh = *(const half4v*)&xr[(size_t)n * 64 + c0];
    float xr0 = (float)xrh[0], xr1 = (float)xrh[1];
    float xr2 = (float)xrh[2], xr3 = (float)xrh[3];
    float4 av  = *(const float4*)&attv[c0];
    int j0 = __builtin_amdgcn_readfirstlane(offs[n]);
    int j1 = __builtin_amdgcn_readfirstlane(offs[n + 1]);
    float l = 0.f;
    float4 acc = {0.f, 0.f, 0.f, 0.f};
    for (int jq = j0; jq < j1; jq += 4) {
        int j = jq + g;
        int jc = (j < j1) ? j : (j1 - 1);
        int s = sperm[jc];
        half4v ev = *(const half4v*)&e4p[(size_t)jc * 64 + c0];
        half4v xlv = *(const half4v*)&xl[(size_t)s * 64 + c0];
        float x0 = (float)xlv[0], x1 = (float)xlv[1];
        float x2 = (float)xlv[2], x3 = (float)xlv[3];
        float h0 = x0 + xr0 + (float)ev[0];
        float h1 = x1 + xr1 + (float)ev[1];
        float h2 = x2 + xr2 + (float)ev[2];
        float h3 = x3 + xr3 + (float)ev[3];
        h0 = (h0 > 0.f) ? h0 : 0.2f * h0;
        h1 = (h1 > 0.f) ? h1 : 0.2f * h1;
        h2 = (h2 > 0.f) ? h2 : 0.2f * h2;
        h3 = (h3 > 0.f) ? h3 : 0.2f * h3;
        float p = h0 * av.x + h1 * av.y + h2 * av.z + h3 * av.w;
        p += __shfl_xor(p, 1); p += __shfl_xor(p, 2);
        p += __shfl_xor(p, 4); p += __shfl_xor(p, 8);
        float w = (j < j1) ? __expf(p) : 0.f;
        l += w;
        acc.x = fmaf(w, x0, acc.x);
        acc.y = fmaf(w, x1, acc.y);
        acc.z = fmaf(w, x2, acc.z);
        acc.w = fmaf(w, x3, acc.w);
    }
    l += __shfl_xor(l, 16); l += __shfl_xor(l, 32);
    acc.x += __shfl_xor(acc.x, 16); acc.x += __shfl_xor(acc.x, 32);
    acc.y += __shfl_xor(acc.y, 16); acc.y += __shfl_xor(acc.y, 32);
    acc.z += __shfl_xor(acc.z, 16); acc.z += __shfl_xor(acc.z, 32);
    acc.w += __shfl_xor(acc.w, 16); acc.w += __shfl_xor(acc.w, 32);
    if (g == 0) {
        float rl = 1.f / (l + 1e-16f);
        float4 bv = *(const float4*)&bias4[c0];
        float4 o;
        o.x = acc.x * rl + bv.x;
        o.y = acc.y * rl + bv.y;
        o.z = acc.z * rl + bv.z;
        o.w = acc.w * rl + bv.w;
        *(float4*)&out[(size_t)n * 64 + c0] = o;
    }
}

// ---------------------------------------------------------------------------
extern "C" void kernel_launch(void* const* d_in, const int* in_sizes, int n_in,
                              void* d_out, int out_size, void* d_ws, size_t ws_size,
                              hipStream_t stream)
{
    const float* x     = (const float*)d_in[0];
    const float* ea    = (const float*)d_in[1];
    const float* eps1  = (const float*)d_in[2];
    const float* w1a   = (const float*)d_in[3];
    const float* b1a   = (const float*)d_in[4];
    const float* w1b   = (const float*)d_in[5];
    const float* b1b   = (const float*)d_in[6];
    const float* we1   = (const float*)d_in[7];
    const float* be1   = (const float*)d_in[8];
    const float* eps2  = (const float*)d_in[9];
    const float* w2a   = (const float*)d_in[10];
    const float* b2a   = (const float*)d_in[11];
    const float* w2b   = (const float*)d_in[12];
    const float* b2b   = (const float*)d_in[13];
    const float* we2   = (const float*)d_in[14];
    const float* be2   = (const float*)d_in[15];
    const float* wq    = (const float*)d_in[16];
    const float* bq    = (const float*)d_in[17];
    const float* wk    = (const float*)d_in[18];
    const float* bk    = (const float*)d_in[19];
    const float* wv    = (const float*)d_in[20];
    const float* bvv   = (const float*)d_in[21];
    const float* we3   = (const float*)d_in[22];
    const float* wskip = (const float*)d_in[23];
    const float* bskip = (const float*)d_in[24];
    const float* wl    = (const float*)d_in[25];
    const float* bl    = (const float*)d_in[26];
    const float* wr    = (const float*)d_in[27];
    const float* br    = (const float*)d_in[28];
    const float* we4   = (const float*)d_in[29];
    const float* attv  = (const float*)d_in[30];
    const float* bias4 = (const float*)d_in[31];
    const void*  eidx  = d_in[32];
    (void)bk;

    const int N = in_sizes[0] / 64;     // 32768
    const int E = in_sizes[1] / 32;     // 524288

    char* ws = (char*)d_ws;
    size_t off = 0;
    auto alloc = [&](size_t bytes) {
        void* p = ws + off;
        off += (bytes + 255) & ~(size_t)255;
        return p;
    };
    int* flag    = (int*)alloc(4);
    int* econv   = (int*)alloc((size_t)2 * E * 4);
    int* counts  = (int*)alloc((size_t)N * 4);
    int* cursor  = (int*)alloc((size_t)N * 4);
    int* offs    = (int*)alloc((size_t)(N + 1) * 4);
    int* perm    = (int*)alloc((size_t)E * 4);
    int* sperm   = (int*)alloc((size_t)E * 4);
    _Float16* xh  = (_Float16*)alloc((size_t)N * 64 * 2);
    _Float16* h16 = (_Float16*)alloc((size_t)N * 64 * 2);
    _Float16* x1h = (_Float16*)alloc((size_t)N * 64 * 2);
    _Float16* x2h = (_Float16*)alloc((size_t)N * 64 * 2);
    _Float16* Wts  = (_Float16*)alloc(16384 * 2);
    _Float16* Gt   = (_Float16*)alloc(16384 * 2);
    _Float16* Wtl  = (_Float16*)alloc(16384 * 2);
    _Float16* Wtr  = (_Float16*)alloc(16384 * 2);
    _Float16* Wt1a = (_Float16*)alloc(4096 * 2);
    _Float16* Wt1b = (_Float16*)alloc(4096 * 2);
    _Float16* Wt2a = (_Float16*)alloc(2048 * 2);
    _Float16* Wt2b = (_Float16*)alloc(2048 * 2);
    _Float16* Mt   = (_Float16*)alloc(8192 * 2);
    float*    cst  = (float*)alloc(128 * 4);
    _Float16* Wt1e = (_Float16*)alloc(2048 * 2);
    _Float16* Wt2e = (_Float16*)alloc(2048 * 2);
    _Float16* Wt4e = (_Float16*)alloc(2048 * 2);
    float*    zt   = (float*)alloc(256 * 4);
    _Float16* Bt3  = (_Float16*)alloc(24576 * 2);
    // big overlaid region R (134 MB)
    char* R = (char*)alloc((size_t)2 * E * 64 * 2);
    // phase 1: e1p/e2p
    _Float16* e1p = (_Float16*)R;
    _Float16* e2p = e1p + (size_t)E * 64;
    // phase 2 (after gine2-2): Y | skiph | qtp | xacc | wab | lb
    _Float16* Yb    = (_Float16*)R;
    _Float16* skiph = Yb + (size_t)N * 256;
    _Float16* qtp   = skiph + (size_t)N * 256;
    _Float16* xaccb = qtp + (size_t)N * 128;
    _Float16* wab   = xaccb + (size_t)N * 256;
    float*    lb    = (float*)(wab + (size_t)N * 128);
    // phase 3 (after gatgemm): e4p over dead Y..skiph..
    _Float16* e4p = (_Float16*)R;
    _Float16* xlh = h16;
    _Float16* xrh = x1h;
    size_t base_off = off;
    _Float16* eap = (_Float16*)alloc((size_t)E * 32 * 2);   // optional 33.5 MB
    int use_eap = (off <= ws_size) ? 1 : 0;

    if (base_off > ws_size) return;   // catastrophic: visible failure

    // weight prep + x fp16
    k_prep<<<512, 256, 0, stream>>>(x, N * 64, wq, wk, wv, wskip, wl, wr,
                                    w1a, w1b, w2a, w2b, we3, bq, we1, we2, we4,
                                    xh, Wts, Gt, Wtl, Wtr,
                                    Wt1a, Wt1b, Wt2a, Wt2b, Mt, cst,
                                    Wt1e, Wt2e, Wt4e, zt, Bt3);

    // edge_index: detect dtype, convert, histogram dst
    k_detect<<<1, 256, 0, stream>>>((const unsigned int*)eidx, flag);
    hipMemsetAsync(counts, 0, (size_t)N * 4, stream);
    k_cvt<<<(2 * E + 255) / 256, 256, 0, stream>>>(eidx, flag, econv, counts, E);
    const int* srcI = econv;
    const int* dstI = econv + E;

    // CSR by dst (pure scatter — no random payload writes)
    k_scan<<<1, 1024, 0, stream>>>(counts, offs, cursor, N);
    k_scatter<<<(E + 255) / 256, 256, 0, stream>>>(dstI, srcI, cursor, perm, sperm, E);

    // e1/e2 materialization: gather-read ea[perm], seq writes (+eap if space)
    if (use_eap)
        k_emm2<1, 1><<<E / 64, 256, 0, stream>>>(ea, perm, Wt1e, be1, e1p,
                                                 Wt2e, be2, e2p, eap);
    else
        k_emm2<0, 1><<<E / 64, 256, 0, stream>>>(ea, perm, Wt1e, be1, e1p,
                                                 Wt2e, be2, e2p, eap);

    // GINE 1 + MLP1
    k_gine2<<<N / 4, 256, 0, stream>>>(xh, e1p, eps1, offs, sperm, h16);
    k_mlp<64><<<N / 64, 256, 0, stream>>>(h16, Wt1a, b1a, Wt1b, b1b, x1h);

    // GINE 2 + MLP2
    k_gine2<<<N / 4, 256, 0, stream>>>(x1h, e2p, eps2, offs, sperm, h16);
    k_mlp<32><<<N / 64, 256, 0, stream>>>(h16, Wt2a, b2a, Wt2b, b2b, x2h);

    // TransformerConv: Y/skip/qt projections, core, epilogue
    k_gemm4m<<<dim3(N / 64, 9), 256, 0, stream>>>(x2h, Gt, Wts, bskip, Mt, cst,
                                                  Yb, skiph, qtp);
    if (use_eap)
        k_tconv5<1><<<N / 4, 256, 0, stream>>>(Yb, qtp, zt, x2h, eap, ea, perm,
                                               offs, sperm, xaccb, wab, lb);
    else
        k_tconv5<0><<<N / 4, 256, 0, stream>>>(Yb, qtp, zt, x2h, eap, ea, perm,
                                               offs, sperm, xaccb, wab, lb);
    k_tpost<<<N / 64, 256, 0, stream>>>(xaccb, wab, lb, Bt3, bvv, skiph);

    // GATv2: projections (reads skiph), then e4p overlay, then aggregation
    k_gatgemm<<<N / 64, 256, 0, stream>>>(skiph, Wtl, bl, Wtr, br, xlh, xrh);
    if (use_eap)
        k_emm<<<E / 64, 256, 0, stream>>>(eap, Wt4e, (const float*)nullptr, e4p);
    else
        k_emm2<0, 0><<<E / 64, 256, 0, stream>>>(ea, perm, Wt4e,
                                                 (const float*)nullptr, e4p,
                                                 (const _Float16*)nullptr,
                                                 (const float*)nullptr,
                                                 (_Float16*)nullptr,
                                                 (_Float16*)nullptr);
    k_gat2<<<N / 4, 256, 0, stream>>>(xlh, xrh, e4p, attv, bias4, offs, sperm,
                                      (float*)d_out);
}

// Round 9
// 347.925 us; speedup vs baseline: 1.0458x; 1.0458x over previous
//
#include <hip/hip_runtime.h>
#include <math.h>

// ---------------------------------------------------------------------------
// N=32768 nodes, E=524288 edges, node feat 64, edge feat 32, H=4 x C=64 = 256.
// MFMA fragment maps (mfma_f32_16x16x32_f16):
//   A(16x32): lane l, reg j -> row=l&15,  k=(l>>4)*8+j
//   B(32x16): lane l, reg j -> col=l&15,  k=(l>>4)*8+j   (store W^T[col][k])
//   C/D:      lane l, reg r -> col=l&15,  row=(l>>4)*4+r
// TransformerConv decomposition (softmax cancels per-(n,h) constants):
//   logit = Y[n]·x2[s] + (0.125 Wk_h bq_h)·x2[s] + qtp[n]·ea   (Y = 0.125 x2·WqWk^T)
//   msg   = (Σw x2[s])@Wv_h + l·bv + (Σw ea)@We3_h             (k_tpost, K=96 MFMA)
// Edge-linear producer (k_emm2): gathers ea[perm[j]] (random L3 reads, fine),
// stages MFMA D-fragments through LDS, and emits FULLY-COALESCED 1KB wave
// stores. R7 lesson: random 64B-granule writes = 30% peak w/ RMW. R8 lesson:
// sequential-but-fragmented (4x32B segments/store) D-fragment stores are just
// as bad — coalesce via LDS round-trip.
// ---------------------------------------------------------------------------

typedef __attribute__((ext_vector_type(2))) _Float16 half2v;
typedef __attribute__((ext_vector_type(4))) _Float16 half4v;
typedef __attribute__((ext_vector_type(8))) _Float16 half8v;
typedef __attribute__((ext_vector_type(4))) float float4v;

// ---------------- edge_index dtype detection + convert(+hist) --------------
__global__ void k_detect(const unsigned int* __restrict__ w, int* __restrict__ flag)
{
    __shared__ int any;
    if (threadIdx.x == 0) any = 0;
    __syncthreads();
    int found = 0;
    for (int i = threadIdx.x; i < 2048; i += 256)
        if (w[2 * i + 1] != 0u) found = 1;
    if (found) atomicOr(&any, 1);
    __syncthreads();
    if (threadIdx.x == 0) flag[0] = any ? 0 : 1;   // 1 => int64
}

__global__ void k_cvt(const void* __restrict__ eidx, const int* __restrict__ flag,
                      int* __restrict__ out, int* __restrict__ counts, int E)
{
    int i = blockIdx.x * blockDim.x + threadIdx.x;
    if (i >= 2 * E) return;
    int v = flag[0] ? (int)((const long long*)eidx)[i] : ((const int*)eidx)[i];
    out[i] = v;
    if (i >= E) atomicAdd(&counts[v], 1);    // dst histogram fused
}

// ---------------- CSR build ------------------------------------------------
__global__ void k_scan(const int* __restrict__ counts, int* __restrict__ offs,
                       int* __restrict__ cursor, int N)
{
    __shared__ int part[1024];
    int t = threadIdx.x;
    int base = t * 32;
    int loc[32];
    int s = 0;
#pragma unroll
    for (int i = 0; i < 32; i++) { loc[i] = counts[base + i]; s += loc[i]; }
    part[t] = s;
    __syncthreads();
    for (int off = 1; off < 1024; off <<= 1) {
        int v = (t >= off) ? part[t - off] : 0;
        __syncthreads();
        part[t] += v;
        __syncthreads();
    }
    int run = part[t] - s;
#pragma unroll
    for (int i = 0; i < 32; i++) {
        offs[base + i] = run;
        cursor[base + i] = run;
        run += loc[i];
    }
    if (t == 1023) offs[N] = run;
}

// pure scatter (no payload): perm/sperm only
__global__ void k_scatter(const int* __restrict__ dst, const int* __restrict__ srcA,
                          int* __restrict__ cursor, int* __restrict__ perm,
                          int* __restrict__ sperm, int E)
{
    int i = blockIdx.x * blockDim.x + threadIdx.x;
    if (i >= E) return;
    int d = dst[i];
    int p = atomicAdd(&cursor[d], 1);
    perm[p] = i;
    sperm[p] = srcA[i];
}

// ---------------- edge-linear via MFMA, gather-read + LDS-coalesced stores -
// wave = 16 edges; lane reads ea[perm[jb+cr]] 32B slice, cvt fp16 in-reg.
// D-fragments staged in LDS then written as 2 x 1KB coalesced wave-stores.
template<int WEAP, int DUAL>
__global__ __launch_bounds__(256) void k_emm2(
    const float* __restrict__ ea, const int* __restrict__ perm,
    const _Float16* __restrict__ WtA, const float* __restrict__ beA,
    _Float16* __restrict__ epA,
    const _Float16* __restrict__ WtB, const float* __restrict__ beB,
    _Float16* __restrict__ epB,
    _Float16* __restrict__ eap)
{
    __shared__ _Float16 st[4][16][72];
    int t = threadIdx.x;
    int wid = t >> 6, l = t & 63;
    int jb = (blockIdx.x * 4 + wid) * 16;
    int cr = l & 15, kg = l >> 4;
    int e = perm[jb + cr];
    const float* ar = ea + (size_t)e * 32 + kg * 8;
    float4 f0 = *(const float4*)ar;
    float4 f1 = *(const float4*)(ar + 4);
    half8v a;
    a[0] = (_Float16)f0.x; a[1] = (_Float16)f0.y;
    a[2] = (_Float16)f0.z; a[3] = (_Float16)f0.w;
    a[4] = (_Float16)f1.x; a[5] = (_Float16)f1.y;
    a[6] = (_Float16)f1.z; a[7] = (_Float16)f1.w;
    if (WEAP)
        *(half8v*)&eap[(size_t)(jb + cr) * 32 + kg * 8] = a;
    _Float16 (*S)[72] = st[wid];
    int rr = l >> 2, cs = (l & 3) * 16;
    // ---- output A ----
#pragma unroll
    for (int c = 0; c < 4; c++) {
        half8v b = *(const half8v*)&WtA[(size_t)(c * 16 + cr) * 32 + kg * 8];
        float4v d = __builtin_amdgcn_mfma_f32_16x16x32_f16(a, b, (float4v){0.f,0.f,0.f,0.f}, 0, 0, 0);
        int col = c * 16 + cr;
        float bv = beA ? beA[col] : 0.f;
#pragma unroll
        for (int r = 0; r < 4; r++)
            S[kg * 4 + r][col] = (_Float16)(d[r] + bv);
    }
    {
        half8v v0 = *(const half8v*)&S[rr][cs];
        half8v v1 = *(const half8v*)&S[rr][cs + 8];
        *(half8v*)&epA[(size_t)(jb + rr) * 64 + cs] = v0;
        *(half8v*)&epA[(size_t)(jb + rr) * 64 + cs + 8] = v1;
    }
    // ---- output B ----
    if (DUAL) {
#pragma unroll
        for (int c = 0; c < 4; c++) {
            half8v b = *(const half8v*)&WtB[(size_t)(c * 16 + cr) * 32 + kg * 8];
            float4v d = __builtin_amdgcn_mfma_f32_16x16x32_f16(a, b, (float4v){0.f,0.f,0.f,0.f}, 0, 0, 0);
            int col = c * 16 + cr;
            float bv = beB ? beB[col] : 0.f;
#pragma unroll
            for (int r = 0; r < 4; r++)
                S[kg * 4 + r][col] = (_Float16)(d[r] + bv);
        }
        half8v v0 = *(const half8v*)&S[rr][cs];
        half8v v1 = *(const half8v*)&S[rr][cs + 8];
        *(half8v*)&epB[(size_t)(jb + rr) * 64 + cs] = v0;
        *(half8v*)&epB[(size_t)(jb + rr) * 64 + cs + 8] = v1;
    }
}

// ---------------- edge-linear via MFMA from sequential eap -----------------
__global__ __launch_bounds__(256) void k_emm(
    const _Float16* __restrict__ eap,
    const _Float16* __restrict__ WtA, const float* __restrict__ beA,
    _Float16* __restrict__ epA)
{
    __shared__ _Float16 st[4][16][72];
    int t = threadIdx.x;
    int wid = t >> 6, l = t & 63;
    int jb = (blockIdx.x * 4 + wid) * 16;
    int cr = l & 15, kg = l >> 4;
    half8v a = *(const half8v*)&eap[(size_t)(jb + cr) * 32 + kg * 8];
    _Float16 (*S)[72] = st[wid];
#pragma unroll
    for (int c = 0; c < 4; c++) {
        half8v b = *(const half8v*)&WtA[(size_t)(c * 16 + cr) * 32 + kg * 8];
        float4v d = __builtin_amdgcn_mfma_f32_16x16x32_f16(a, b, (float4v){0.f,0.f,0.f,0.f}, 0, 0, 0);
        int col = c * 16 + cr;
        float bv = beA ? beA[col] : 0.f;
#pragma unroll
        for (int r = 0; r < 4; r++)
            S[kg * 4 + r][col] = (_Float16)(d[r] + bv);
    }
    int rr = l >> 2, cs = (l & 3) * 16;
    half8v v0 = *(const half8v*)&S[rr][cs];
    half8v v1 = *(const half8v*)&S[rr][cs + 8];
    *(half8v*)&epA[(size_t)(jb + rr) * 64 + cs] = v0;
    *(half8v*)&epA[(size_t)(jb + rr) * 64 + cs + 8] = v1;
}

// ---------------- weight prep ----------------------------------------------
__global__ __launch_bounds__(256) void k_prep(
    const float* __restrict__ x, int NX,
    const float* __restrict__ wq, const float* __restrict__ wk,
    const float* __restrict__ wv, const float* __restrict__ wskip,
    const float* __restrict__ wl, const float* __restrict__ wr,
    const float* __restrict__ w1a, const float* __restrict__ w1b,
    const float* __restrict__ w2a, const float* __restrict__ w2b,
    const float* __restrict__ we3, const float* __restrict__ bq,
    const float* __restrict__ we1, const float* __restrict__ we2,
    const float* __restrict__ we4,
    _Float16* __restrict__ xh,
    _Float16* __restrict__ Wts, _Float16* __restrict__ Gt,
    _Float16* __restrict__ Wtl, _Float16* __restrict__ Wtr,
    _Float16* __restrict__ Wt1a, _Float16* __restrict__ Wt1b,
    _Float16* __restrict__ Wt2a, _Float16* __restrict__ Wt2b,
    _Float16* __restrict__ Mt, float* __restrict__ cst,
    _Float16* __restrict__ Wt1e, _Float16* __restrict__ Wt2e,
    _Float16* __restrict__ Wt4e, float* __restrict__ zt,
    _Float16* __restrict__ Bt3)
{
    int g = blockIdx.x * 256 + threadIdx.x;
    if (g < 16384) {                       // Wts[c<256][k<64]
        int c = g >> 6, k = g & 63;
        Wts[g] = (_Float16)wskip[(size_t)k * 256 + c];
    } else if (g < 32768) {                // Gt[col<256][d<64] = 0.125 WqWk^T
        int q = g - 16384, col = q >> 6, d = q & 63;
        int h = col >> 6, c = col & 63;
        float s = 0.f;
        for (int mq = 0; mq < 64; mq++)
            s = fmaf(wq[(size_t)d * 256 + h * 64 + mq],
                     wk[(size_t)c * 256 + h * 64 + mq], s);
        Gt[q] = (_Float16)(0.125f * s);
    } else if (g < 49152) {                // wl/wr: Wt[c<64][k<256]
        int q = g - 32768, c = q >> 8, k = q & 255;
        Wtl[q] = (_Float16)wl[(size_t)k * 64 + c];
        Wtr[q] = (_Float16)wr[(size_t)k * 64 + c];
    } else if (g < 53248) {                // w1a/w1b 64x64
        int q = g - 49152, m = q >> 6, k = q & 63;
        Wt1a[q] = (_Float16)w1a[(size_t)k * 64 + m];
        Wt1b[q] = (_Float16)w1b[(size_t)k * 64 + m];
    } else if (g < 55296) {                // w2a -> Wt2a[m<32][k<64]
        int q = g - 53248, m = q >> 6, k = q & 63;
        Wt2a[q] = (_Float16)w2a[(size_t)k * 32 + m];
    } else if (g < 57344) {                // w2b -> Wt2b[c<64][k<32]
        int q = g - 55296, c = q >> 5, k = q & 31;
        Wt2b[q] = (_Float16)w2b[(size_t)k * 64 + c];
    } else if (g < 65536) {                // Mt[m<128][d<64]
        int q = g - 57344, m = q >> 6, d = q & 63;
        int h = m >> 5, kk = m & 31;
        float s = 0.f;
        for (int c = 0; c < 64; c++)
            s = fmaf(wq[(size_t)d * 256 + h * 64 + c],
                     we3[(size_t)kk * 256 + h * 64 + c], s);
        Mt[q] = (_Float16)(0.125f * s);
    } else if (g < 65664) {                // cst[128]
        int m = g - 65536, h = m >> 5, kk = m & 31;
        float s = 0.f;
        for (int c = 0; c < 64; c++)
            s = fmaf(bq[h * 64 + c], we3[(size_t)kk * 256 + h * 64 + c], s);
        cst[m] = 0.125f * s;
    } else if (g < 67712) {                // Wt1e[c<64][k<32]
        int q = g - 65664, c = q >> 5, k = q & 31;
        Wt1e[q] = (_Float16)we1[(size_t)k * 64 + c];
    } else if (g < 69760) {
        int q = g - 67712, c = q >> 5, k = q & 31;
        Wt2e[q] = (_Float16)we2[(size_t)k * 64 + c];
    } else if (g < 71808) {
        int q = g - 69760, c = q >> 5, k = q & 31;
        Wt4e[q] = (_Float16)we4[(size_t)k * 64 + c];
    } else if (g < 72064) {                // zt[h*64+c] = 0.125 Wk_h^T bq_h
        int q = g - 71808, h = q >> 6, c = q & 63;
        float s = 0.f;
        for (int mq = 0; mq < 64; mq++)
            s = fmaf(wk[(size_t)c * 256 + h * 64 + mq], bq[h * 64 + mq], s);
        zt[q] = 0.125f * s;
    } else if (g < 96640) {                // Bt3[(h*64+col)*96 + k]
        int q = g - 72064;
        int hc = q / 96, k = q - hc * 96;
        int h = hc >> 6, col = hc & 63;
        float v = (k < 64) ? wv[(size_t)k * 256 + h * 64 + col]
                           : we3[(size_t)(k - 64) * 256 + h * 64 + col];
        Bt3[q] = (_Float16)v;
    }
    for (int i = g; i < NX; i += 512 * 256)
        xh[i] = (_Float16)x[i];
}

// ---------------- fused 2-layer MLP via MFMA -------------------------------
template<int MID>
__global__ __launch_bounds__(256) void k_mlp(
    const _Float16* __restrict__ A,
    const _Float16* __restrict__ Wt1, const float* __restrict__ b1,
    const _Float16* __restrict__ Wt2, const float* __restrict__ b2,
    _Float16* __restrict__ out)
{
    __shared__ _Float16 As[64][72];
    __shared__ _Float16 Ws1[MID][72];
    __shared__ _Float16 Ws2[64][MID + 8];
    __shared__ _Float16 mids[64][MID + 8];
    int t = threadIdx.x;
    int n0 = blockIdx.x * 64;
    for (int f = t; f < 512; f += 256) {
        int r = f >> 3, seg = f & 7;
        *(uint4*)&As[r][seg * 8] = *(const uint4*)&A[(size_t)(n0 + r) * 64 + seg * 8];
    }
    for (int f = t; f < MID * 8; f += 256) {
        int r = f >> 3, seg = f & 7;
        *(uint4*)&Ws1[r][seg * 8] = *(const uint4*)&Wt1[(size_t)r * 64 + seg * 8];
    }
    constexpr int CH = MID / 8;
    for (int f = t; f < 64 * CH; f += 256) {
        int r = f / CH, seg = f % CH;
        *(uint4*)&Ws2[r][seg * 8] = *(const uint4*)&Wt2[(size_t)r * MID + seg * 8];
    }
    __syncthreads();
    int w = t >> 6, l = t & 63;
    int arow = w * 16 + (l & 15);
    int kg = (l >> 4) * 8;
    int colg = l & 15;
    int orow = w * 16 + (l >> 4) * 4;
    half8v a0 = *(const half8v*)&As[arow][kg];
    half8v a1 = *(const half8v*)&As[arow][32 + kg];
    constexpr int NCT1 = MID / 16;
#pragma unroll
    for (int ct = 0; ct < NCT1; ct++) {
        half8v b0 = *(const half8v*)&Ws1[ct * 16 + colg][kg];
        half8v b1v = *(const half8v*)&Ws1[ct * 16 + colg][32 + kg];
        float4v acc = {0.f, 0.f, 0.f, 0.f};
        acc = __builtin_amdgcn_mfma_f32_16x16x32_f16(a0, b0, acc, 0, 0, 0);
        acc = __builtin_amdgcn_mfma_f32_16x16x32_f16(a1, b1v, acc, 0, 0, 0);
        int col = ct * 16 + colg;
        float bb = b1[col];
#pragma unroll
        for (int r = 0; r < 4; r++)
            mids[orow + r][col] = (_Float16)fmaxf(acc[r] + bb, 0.f);
    }
    __syncthreads();
    half8v m0 = *(const half8v*)&mids[arow][kg];
#pragma unroll
    for (int ct = 0; ct < 4; ct++) {
        half8v b0 = *(const half8v*)&Ws2[ct * 16 + colg][kg];
        float4v acc = {0.f, 0.f, 0.f, 0.f};
        acc = __builtin_amdgcn_mfma_f32_16x16x32_f16(m0, b0, acc, 0, 0, 0);
        if (MID == 64) {
            half8v m1 = *(const half8v*)&mids[arow][32 + kg];
            half8v b1v = *(const half8v*)&Ws2[ct * 16 + colg][32 + kg];
            acc = __builtin_amdgcn_mfma_f32_16x16x32_f16(m1, b1v, acc, 0, 0, 0);
        }
        int col = ct * 16 + colg;
        float bb = b2[col];
#pragma unroll
        for (int r = 0; r < 4; r++)
            out[(size_t)(n0 + orow + r) * 64 + col] = (_Float16)(acc[r] + bb);
    }
}

// ---------------- fused Y/skip/qt projections via MFMA ---------------------
// grid (N/64, 9): y<4 -> Y tile; y<8 -> skip tile; y==8 -> qt.
__global__ __launch_bounds__(256) void k_gemm4m(
    const _Float16* __restrict__ A,
    const _Float16* __restrict__ Gt,
    const _Float16* __restrict__ Wts, const float* __restrict__ bs,
    const _Float16* __restrict__ Mt,  const float* __restrict__ cst,
    _Float16* __restrict__ Yb, _Float16* __restrict__ skiph,
    _Float16* __restrict__ qtp)
{
    __shared__ _Float16 As[64][72];
    __shared__ _Float16 Ws[128][72];
    int t = threadIdx.x;
    int n0 = blockIdx.x * 64;
    int y = blockIdx.y;
    for (int f = t; f < 512; f += 256) {
        int r = f >> 3, seg = f & 7;
        *(uint4*)&As[r][seg * 8] = *(const uint4*)&A[(size_t)(n0 + r) * 64 + seg * 8];
    }
    if (y < 8) {
        int j0 = (y & 3) * 64;
        const _Float16* Wt = (y < 4) ? Gt : Wts;
        for (int f = t; f < 512; f += 256) {
            int c = f >> 3, seg = f & 7;
            *(uint4*)&Ws[c][seg * 8] = *(const uint4*)&Wt[(size_t)(j0 + c) * 64 + seg * 8];
        }
    } else {
        for (int f = t; f < 1024; f += 256) {
            int c = f >> 3, seg = f & 7;
            *(uint4*)&Ws[c][seg * 8] = *(const uint4*)&Mt[(size_t)c * 64 + seg * 8];
        }
    }
    __syncthreads();
    int w = t >> 6, l = t & 63;
    int arow = w * 16 + (l & 15);
    int kg = (l >> 4) * 8;
    int colg = l & 15;
    int orow = w * 16 + (l >> 4) * 4;
    half8v a0 = *(const half8v*)&As[arow][kg];
    half8v a1 = *(const half8v*)&As[arow][32 + kg];
    if (y < 8) {
        int j0 = (y & 3) * 64;
        _Float16* O = (y < 4) ? Yb : skiph;
#pragma unroll
        for (int ct = 0; ct < 4; ct++) {
            half8v b0 = *(const half8v*)&Ws[ct * 16 + colg][kg];
            half8v b1 = *(const half8v*)&Ws[ct * 16 + colg][32 + kg];
            float4v a = {0.f, 0.f, 0.f, 0.f};
            a = __builtin_amdgcn_mfma_f32_16x16x32_f16(a0, b0, a, 0, 0, 0);
            a = __builtin_amdgcn_mfma_f32_16x16x32_f16(a1, b1, a, 0, 0, 0);
            int col = j0 + ct * 16 + colg;
            float bb = (y < 4) ? 0.f : bs[col];
#pragma unroll
            for (int r = 0; r < 4; r++)
                O[(size_t)(n0 + orow + r) * 256 + col] = (_Float16)(a[r] + bb);
        }
    } else {
#pragma unroll
        for (int ct = 0; ct < 8; ct++) {
            half8v b0 = *(const half8v*)&Ws[ct * 16 + colg][kg];
            half8v b1 = *(const half8v*)&Ws[ct * 16 + colg][32 + kg];
            float4v a = {0.f, 0.f, 0.f, 0.f};
            a = __builtin_amdgcn_mfma_f32_16x16x32_f16(a0, b0, a, 0, 0, 0);
            a = __builtin_amdgcn_mfma_f32_16x16x32_f16(a1, b1, a, 0, 0, 0);
            int col = ct * 16 + colg;
            float bb = cst[col];
#pragma unroll
            for (int r = 0; r < 4; r++)
                qtp[(size_t)(n0 + orow + r) * 128 + col] = (_Float16)(a[r] + bb);
        }
    }
}

// ---------------- GINE aggregation, quad layout ----------------------------
__global__ __launch_bounds__(256) void k_gine2(
    const _Float16* __restrict__ xin, const _Float16* __restrict__ ep,
    const float* __restrict__ epsp,
    const int* __restrict__ offs, const int* __restrict__ sperm,
    _Float16* __restrict__ hout)
{
    int t = threadIdx.x;
    int wid  = __builtin_amdgcn_readfirstlane(t >> 6);
    int n    = blockIdx.x * 4 + wid;
    int lane = t & 63;
    int g = lane >> 4, li = lane & 15, c0 = li * 4;
    int j0 = __builtin_amdgcn_readfirstlane(offs[n]);
    int j1 = __builtin_amdgcn_readfirstlane(offs[n + 1]);
    float4 acc = {0.f, 0.f, 0.f, 0.f};
    for (int jq = j0; jq < j1; jq += 4) {
        int j = jq + g;
        int jc = (j < j1) ? j : (j1 - 1);
        int s = sperm[jc];
        half4v ev = *(const half4v*)&ep[(size_t)jc * 64 + c0];
        half4v xv = *(const half4v*)&xin[(size_t)s * 64 + c0];
        if (j < j1) {
            acc.x += fmaxf((float)xv[0] + (float)ev[0], 0.f);
            acc.y += fmaxf((float)xv[1] + (float)ev[1], 0.f);
            acc.z += fmaxf((float)xv[2] + (float)ev[2], 0.f);
            acc.w += fmaxf((float)xv[3] + (float)ev[3], 0.f);
        }
    }
    acc.x += __shfl_xor(acc.x, 16); acc.x += __shfl_xor(acc.x, 32);
    acc.y += __shfl_xor(acc.y, 16); acc.y += __shfl_xor(acc.y, 32);
    acc.z += __shfl_xor(acc.z, 16); acc.z += __shfl_xor(acc.z, 32);
    acc.w += __shfl_xor(acc.w, 16); acc.w += __shfl_xor(acc.w, 32);
    if (g == 0) {
        float eps1 = 1.f + epsp[0];
        half4v xn = *(const half4v*)&xin[(size_t)n * 64 + c0];
        half4v o;
        o[0] = (_Float16)(eps1 * (float)xn[0] + acc.x);
        o[1] = (_Float16)(eps1 * (float)xn[1] + acc.y);
        o[2] = (_Float16)(eps1 * (float)xn[2] + acc.z);
        o[3] = (_Float16)(eps1 * (float)xn[3] + acc.w);
        *(half4v*)&hout[(size_t)n * 64 + c0] = o;
    }
}

// ---------------- TransformerConv core: x2-gather only ---------------------
// wave = node; lane = h*16 + c; lane covers x2 channels [c*4, c*4+4).
template<int USE_EAP>
__global__ __launch_bounds__(256) void k_tconv5(
    const _Float16* __restrict__ Yb, const _Float16* __restrict__ qtp,
    const float* __restrict__ zt, const _Float16* __restrict__ x2h,
    const _Float16* __restrict__ eap, const float* __restrict__ ea,
    const int* __restrict__ perm, const int* __restrict__ offs,
    const int* __restrict__ sperm,
    _Float16* __restrict__ xaccb, _Float16* __restrict__ wab,
    float* __restrict__ lb)
{
    int t = threadIdx.x;
    int wid = __builtin_amdgcn_readfirstlane(t >> 6);
    int n = blockIdx.x * 4 + wid;
    int lane = t & 63;
    int h = lane >> 4, c = lane & 15;
    float yb0, yb1, yb2, yb3;
    {
        half4v Y4 = *(const half4v*)&Yb[(size_t)n * 256 + h * 64 + c * 4];
        float4 z4 = *(const float4*)&zt[h * 64 + c * 4];
        yb0 = (float)Y4[0] + z4.x; yb1 = (float)Y4[1] + z4.y;
        yb2 = (float)Y4[2] + z4.z; yb3 = (float)Y4[3] + z4.w;
    }
    half2v qt2 = *(const half2v*)&qtp[(size_t)n * 128 + h * 32 + c * 2];
    float qt0 = (float)qt2[0], qt1 = (float)qt2[1];
    int j0 = __builtin_amdgcn_readfirstlane(offs[n]);
    int j1 = __builtin_amdgcn_readfirstlane(offs[n + 1]);
    float l = 0.f;
    float xa0 = 0.f, xa1 = 0.f, xa2 = 0.f, xa3 = 0.f;
    float wa0 = 0.f, wa1 = 0.f;
    int j = j0;
    for (; j + 1 < j1; j += 2) {
        int s0 = __builtin_amdgcn_readfirstlane(sperm[j]);
        int s1 = __builtin_amdgcn_readfirstlane(sperm[j + 1]);
        half4v xA = *(const half4v*)&x2h[(size_t)s0 * 64 + c * 4];
        half4v xB = *(const half4v*)&x2h[(size_t)s1 * 64 + c * 4];
        float eA0, eA1, eB0, eB1;
        if (USE_EAP) {
            half2v vA = *(const half2v*)&eap[(size_t)j * 32 + c * 2];
            half2v vB = *(const half2v*)&eap[(size_t)(j + 1) * 32 + c * 2];
            eA0 = (float)vA[0]; eA1 = (float)vA[1];
            eB0 = (float)vB[0]; eB1 = (float)vB[1];
        } else {
            int e0 = __builtin_amdgcn_readfirstlane(perm[j]);
            int e1 = __builtin_amdgcn_readfirstlane(perm[j + 1]);
            float2 fA = *(const float2*)&ea[(size_t)e0 * 32 + c * 2];
            float2 fB = *(const float2*)&ea[(size_t)e1 * 32 + c * 2];
            eA0 = fA.x; eA1 = fA.y; eB0 = fB.x; eB1 = fB.y;
        }
        float xA0 = (float)xA[0], xA1f = (float)xA[1];
        float xA2 = (float)xA[2], xA3 = (float)xA[3];
        float xB0 = (float)xB[0], xB1f = (float)xB[1];
        float xB2 = (float)xB[2], xB3 = (float)xB[3];
        float p0 = yb0 * xA0 + yb1 * xA1f + yb2 * xA2 + yb3 * xA3
                 + qt0 * eA0 + qt1 * eA1;
        float p1 = yb0 * xB0 + yb1 * xB1f + yb2 * xB2 + yb3 * xB3
                 + qt0 * eB0 + qt1 * eB1;
        p0 += __shfl_xor(p0, 1); p1 += __shfl_xor(p1, 1);
        p0 += __shfl_xor(p0, 2); p1 += __shfl_xor(p1, 2);
        p0 += __shfl_xor(p0, 4); p1 += __shfl_xor(p1, 4);
        p0 += __shfl_xor(p0, 8); p1 += __shfl_xor(p1, 8);
        float w0 = __expf(p0), w1 = __expf(p1);   // logits O(0.5): no-max exact
        l += w0 + w1;
        xa0 += w0 * xA0 + w1 * xB0;
        xa1 += w0 * xA1f + w1 * xB1f;
        xa2 += w0 * xA2 + w1 * xB2;
        xa3 += w0 * xA3 + w1 * xB3;
        wa0 += w0 * eA0 + w1 * eB0;
        wa1 += w0 * eA1 + w1 * eB1;
    }
    if (j < j1) {
        int s0 = __builtin_amdgcn_readfirstlane(sperm[j]);
        half4v xA = *(const half4v*)&x2h[(size_t)s0 * 64 + c * 4];
        float eA0, eA1;
        if (USE_EAP) {
            half2v vA = *(const half2v*)&eap[(size_t)j * 32 + c * 2];
            eA0 = (float)vA[0]; eA1 = (float)vA[1];
        } else {
            int e0 = __builtin_amdgcn_readfirstlane(perm[j]);
            float2 fA = *(const float2*)&ea[(size_t)e0 * 32 + c * 2];
            eA0 = fA.x; eA1 = fA.y;
        }
        float xA0 = (float)xA[0], xA1f = (float)xA[1];
        float xA2 = (float)xA[2], xA3 = (float)xA[3];
        float p0 = yb0 * xA0 + yb1 * xA1f + yb2 * xA2 + yb3 * xA3
                 + qt0 * eA0 + qt1 * eA1;
        p0 += __shfl_xor(p0, 1); p0 += __shfl_xor(p0, 2);
        p0 += __shfl_xor(p0, 4); p0 += __shfl_xor(p0, 8);
        float w0 = __expf(p0);
        l += w0;
        xa0 += w0 * xA0; xa1 += w0 * xA1f; xa2 += w0 * xA2; xa3 += w0 * xA3;
        wa0 += w0 * eA0; wa1 += w0 * eA1;
    }
    half4v xo;
    xo[0] = (_Float16)xa0; xo[1] = (_Float16)xa1;
    xo[2] = (_Float16)xa2; xo[3] = (_Float16)xa3;
    *(half4v*)&xaccb[(size_t)n * 256 + h * 64 + c * 4] = xo;
    half2v wo;
    wo[0] = (_Float16)wa0; wo[1] = (_Float16)wa1;
    *(half2v*)&wab[(size_t)n * 128 + h * 32 + c * 2] = wo;
    if (c == 0) lb[n * 4 + h] = l;
}

// ---------------- tconv epilogue: out = ([xacc|wa]@[Wv;We3])/l + bv + skip -
__global__ __launch_bounds__(256) void k_tpost(
    const _Float16* __restrict__ xaccb, const _Float16* __restrict__ wab,
    const float* __restrict__ lb, const _Float16* __restrict__ Bt3,
    const float* __restrict__ bv, _Float16* __restrict__ skiph)
{
    int t = threadIdx.x;
    int h = t >> 6;
    int l = t & 63;
    int n0 = blockIdx.x * 64;
    int colg = l & 15, kg = (l >> 4) * 8;
    half8v Bf[4][3];
#pragma unroll
    for (int ct = 0; ct < 4; ct++) {
        size_t cb = (size_t)(h * 64 + ct * 16 + colg) * 96;
        Bf[ct][0] = *(const half8v*)&Bt3[cb + kg];
        Bf[ct][1] = *(const half8v*)&Bt3[cb + 32 + kg];
        Bf[ct][2] = *(const half8v*)&Bt3[cb + 64 + kg];
    }
#pragma unroll
    for (int rt = 0; rt < 4; rt++) {
        int arow = n0 + rt * 16 + (l & 15);
        half8v A0 = *(const half8v*)&xaccb[(size_t)arow * 256 + h * 64 + kg];
        half8v A1 = *(const half8v*)&xaccb[(size_t)arow * 256 + h * 64 + 32 + kg];
        half8v A2 = *(const half8v*)&wab[(size_t)arow * 128 + h * 32 + kg];
#pragma unroll
        for (int ct = 0; ct < 4; ct++) {
            float4v acc = {0.f, 0.f, 0.f, 0.f};
            acc = __builtin_amdgcn_mfma_f32_16x16x32_f16(A0, Bf[ct][0], acc, 0, 0, 0);
            acc = __builtin_amdgcn_mfma_f32_16x16x32_f16(A1, Bf[ct][1], acc, 0, 0, 0);
            acc = __builtin_amdgcn_mfma_f32_16x16x32_f16(A2, Bf[ct][2], acc, 0, 0, 0);
            int col = h * 64 + ct * 16 + colg;
            float bvc = bv[col];
#pragma unroll
            for (int r = 0; r < 4; r++) {
                int row = n0 + rt * 16 + (l >> 4) * 4 + r;
                float lv = lb[row * 4 + h];
                float rl = (lv > 0.f) ? 1.f / lv : 0.f;
                float bterm = (lv > 0.f) ? bvc : 0.f;
                size_t o = (size_t)row * 256 + col;
                float out = acc[r] * rl + bterm + (float)skiph[o];
                skiph[o] = (_Float16)out;
            }
        }
    }
}

// ---------------- GAT xl/xr projections (fused L+R, fp16 A) ----------------
__global__ __launch_bounds__(256) void k_gatgemm(
    const _Float16* __restrict__ A,
    const _Float16* __restrict__ WtL, const float* __restrict__ bL,
    const _Float16* __restrict__ WtR, const float* __restrict__ bR,
    _Float16* __restrict__ xlh, _Float16* __restrict__ xrh)
{
    __shared__ _Float16 As[64][136];
    __shared__ _Float16 WsL[64][136];
    __shared__ _Float16 WsR[64][136];
    int t = threadIdx.x;
    int n0 = blockIdx.x * 64;
    int w = t >> 6, l = t & 63;
    int arow = w * 16 + (l & 15);
    int kg = (l >> 4) * 8;
    int colg = l & 15;
    int orow = w * 16 + (l >> 4) * 4;
    float4v accL[4] = {{0.f,0.f,0.f,0.f},{0.f,0.f,0.f,0.f},
                       {0.f,0.f,0.f,0.f},{0.f,0.f,0.f,0.f}};
    float4v accR[4] = {{0.f,0.f,0.f,0.f},{0.f,0.f,0.f,0.f},
                       {0.f,0.f,0.f,0.f},{0.f,0.f,0.f,0.f}};
    for (int kh = 0; kh < 2; kh++) {
        __syncthreads();
        for (int f = t; f < 1024; f += 256) {
            int r = f >> 4, seg = f & 15;
            *(uint4*)&As[r][seg * 8] =
                *(const uint4*)&A[(size_t)(n0 + r) * 256 + kh * 128 + seg * 8];
            *(uint4*)&WsL[r][seg * 8] =
                *(const uint4*)&WtL[(size_t)r * 256 + kh * 128 + seg * 8];
            *(uint4*)&WsR[r][seg * 8] =
                *(const uint4*)&WtR[(size_t)r * 256 + kh * 128 + seg * 8];
        }
        __syncthreads();
#pragma unroll
        for (int ks = 0; ks < 4; ks++) {
            half8v a = *(const half8v*)&As[arow][ks * 32 + kg];
#pragma unroll
            for (int ct = 0; ct < 4; ct++) {
                half8v bl_ = *(const half8v*)&WsL[ct * 16 + colg][ks * 32 + kg];
                half8v br_ = *(const half8v*)&WsR[ct * 16 + colg][ks * 32 + kg];
                accL[ct] = __builtin_amdgcn_mfma_f32_16x16x32_f16(a, bl_, accL[ct], 0, 0, 0);
                accR[ct] = __builtin_amdgcn_mfma_f32_16x16x32_f16(a, br_, accR[ct], 0, 0, 0);
            }
        }
    }
#pragma unroll
    for (int ct = 0; ct < 4; ct++) {
        int col = ct * 16 + colg;
        float bvL = bL[col], bvR = bR[col];
#pragma unroll
        for (int r = 0; r < 4; r++) {
            xlh[(size_t)(n0 + orow + r) * 64 + col] = (_Float16)(accL[ct][r] + bvL);
            xrh[(size_t)(n0 + orow + r) * 64 + col] = (_Float16)(accR[ct][r] + bvR);
        }
    }
}

// ---------------- GATv2 aggregation, quad layout ---------------------------
__global__ __launch_bounds__(256) void k_gat2(
    const _Float16* __restrict__ xl, const _Float16* __restrict__ xr,
    const _Float16* __restrict__ e4p,
    const float* __restrict__ attv, const float* __restrict__ bias4,
    const int* __restrict__ offs, const int* __restrict__ sperm,
    float* __restrict__ out)
{
    int t = threadIdx.x;
    int wid  = __builtin_amdgcn_readfirstlane(t >> 6);
    int n    = blockIdx.x * 4 + wid;
    int lane = t & 63;
    int g = lane >> 4, li = lane & 15, c0 = li * 4;
    half4v xrh = *(const half4v*)&xr[(size_t)n * 64 + c0];
    float xr0 = (float)xrh[0], xr1 = (float)xrh[1];
    float xr2 = (float)xrh[2], xr3 = (float)xrh[3];
    float4 av  = *(const float4*)&attv[c0];
    int j0 = __builtin_amdgcn_readfirstlane(offs[n]);
    int j1 = __builtin_amdgcn_readfirstlane(offs[n + 1]);
    float l = 0.f;
    float4 acc = {0.f, 0.f, 0.f, 0.f};
    for (int jq = j0; jq < j1; jq += 4) {
        int j = jq + g;
        int jc = (j < j1) ? j : (j1 - 1);
        int s = sperm[jc];
        half4v ev = *(const half4v*)&e4p[(size_t)jc * 64 + c0];
        half4v xlv = *(const half4v*)&xl[(size_t)s * 64 + c0];
        float x0 = (float)xlv[0], x1 = (float)xlv[1];
        float x2 = (float)xlv[2], x3 = (float)xlv[3];
        float h0 = x0 + xr0 + (float)ev[0];
        float h1 = x1 + xr1 + (float)ev[1];
        float h2 = x2 + xr2 + (float)ev[2];
        float h3 = x3 + xr3 + (float)ev[3];
        h0 = (h0 > 0.f) ? h0 : 0.2f * h0;
        h1 = (h1 > 0.f) ? h1 : 0.2f * h1;
        h2 = (h2 > 0.f) ? h2 : 0.2f * h2;
        h3 = (h3 > 0.f) ? h3 : 0.2f * h3;
        float p = h0 * av.x + h1 * av.y + h2 * av.z + h3 * av.w;
        p += __shfl_xor(p, 1); p += __shfl_xor(p, 2);
        p += __shfl_xor(p, 4); p += __shfl_xor(p, 8);
        float w = (j < j1) ? __expf(p) : 0.f;
        l += w;
        acc.x = fmaf(w, x0, acc.x);
        acc.y = fmaf(w, x1, acc.y);
        acc.z = fmaf(w, x2, acc.z);
        acc.w = fmaf(w, x3, acc.w);
    }
    l += __shfl_xor(l, 16); l += __shfl_xor(l, 32);
    acc.x += __shfl_xor(acc.x, 16); acc.x += __shfl_xor(acc.x, 32);
    acc.y += __shfl_xor(acc.y, 16); acc.y += __shfl_xor(acc.y, 32);
    acc.z += __shfl_xor(acc.z, 16); acc.z += __shfl_xor(acc.z, 32);
    acc.w += __shfl_xor(acc.w, 16); acc.w += __shfl_xor(acc.w, 32);
    if (g == 0) {
        float rl = 1.f / (l + 1e-16f);
        float4 bv = *(const float4*)&bias4[c0];
        float4 o;
        o.x = acc.x * rl + bv.x;
        o.y = acc.y * rl + bv.y;
        o.z = acc.z * rl + bv.z;
        o.w = acc.w * rl + bv.w;
        *(float4*)&out[(size_t)n * 64 + c0] = o;
    }
}

// ---------------------------------------------------------------------------
extern "C" void kernel_launch(void* const* d_in, const int* in_sizes, int n_in,
                              void* d_out, int out_size, void* d_ws, size_t ws_size,
                              hipStream_t stream)
{
    const float* x     = (const float*)d_in[0];
    const float* ea    = (const float*)d_in[1];
    const float* eps1  = (const float*)d_in[2];
    const float* w1a   = (const float*)d_in[3];
    const float* b1a   = (const float*)d_in[4];
    const float* w1b   = (const float*)d_in[5];
    const float* b1b   = (const float*)d_in[6];
    const float* we1   = (const float*)d_in[7];
    const float* be1   = (const float*)d_in[8];
    const float* eps2  = (const float*)d_in[9];
    const float* w2a   = (const float*)d_in[10];
    const float* b2a   = (const float*)d_in[11];
    const float* w2b   = (const float*)d_in[12];
    const float* b2b   = (const float*)d_in[13];
    const float* we2   = (const float*)d_in[14];
    const float* be2   = (const float*)d_in[15];
    const float* wq    = (const float*)d_in[16];
    const float* bq    = (const float*)d_in[17];
    const float* wk    = (const float*)d_in[18];
    const float* bk    = (const float*)d_in[19];
    const float* wv    = (const float*)d_in[20];
    const float* bvv   = (const float*)d_in[21];
    const float* we3   = (const float*)d_in[22];
    const float* wskip = (const float*)d_in[23];
    const float* bskip = (const float*)d_in[24];
    const float* wl    = (const float*)d_in[25];
    const float* bl    = (const float*)d_in[26];
    const float* wr    = (const float*)d_in[27];
    const float* br    = (const float*)d_in[28];
    const float* we4   = (const float*)d_in[29];
    const float* attv  = (const float*)d_in[30];
    const float* bias4 = (const float*)d_in[31];
    const void*  eidx  = d_in[32];
    (void)bk;

    const int N = in_sizes[0] / 64;     // 32768
    const int E = in_sizes[1] / 32;     // 524288

    char* ws = (char*)d_ws;
    size_t off = 0;
    auto alloc = [&](size_t bytes) {
        void* p = ws + off;
        off += (bytes + 255) & ~(size_t)255;
        return p;
    };
    int* flag    = (int*)alloc(4);
    int* econv   = (int*)alloc((size_t)2 * E * 4);
    int* counts  = (int*)alloc((size_t)N * 4);
    int* cursor  = (int*)alloc((size_t)N * 4);
    int* offs    = (int*)alloc((size_t)(N + 1) * 4);
    int* perm    = (int*)alloc((size_t)E * 4);
    int* sperm   = (int*)alloc((size_t)E * 4);
    _Float16* xh  = (_Float16*)alloc((size_t)N * 64 * 2);
    _Float16* h16 = (_Float16*)alloc((size_t)N * 64 * 2);
    _Float16* x1h = (_Float16*)alloc((size_t)N * 64 * 2);
    _Float16* x2h = (_Float16*)alloc((size_t)N * 64 * 2);
    _Float16* Wts  = (_Float16*)alloc(16384 * 2);
    _Float16* Gt   = (_Float16*)alloc(16384 * 2);
    _Float16* Wtl  = (_Float16*)alloc(16384 * 2);
    _Float16* Wtr  = (_Float16*)alloc(16384 * 2);
    _Float16* Wt1a = (_Float16*)alloc(4096 * 2);
    _Float16* Wt1b = (_Float16*)alloc(4096 * 2);
    _Float16* Wt2a = (_Float16*)alloc(2048 * 2);
    _Float16* Wt2b = (_Float16*)alloc(2048 * 2);
    _Float16* Mt   = (_Float16*)alloc(8192 * 2);
    float*    cst  = (float*)alloc(128 * 4);
    _Float16* Wt1e = (_Float16*)alloc(2048 * 2);
    _Float16* Wt2e = (_Float16*)alloc(2048 * 2);
    _Float16* Wt4e = (_Float16*)alloc(2048 * 2);
    float*    zt   = (float*)alloc(256 * 4);
    _Float16* Bt3  = (_Float16*)alloc(24576 * 2);
    // big overlaid region R (134 MB)
    char* R = (char*)alloc((size_t)2 * E * 64 * 2);
    // phase 1: e1p/e2p
    _Float16* e1p = (_Float16*)R;
    _Float16* e2p = e1p + (size_t)E * 64;
    // phase 2 (after gine2-2): Y | skiph | qtp | xacc | wab | lb
    _Float16* Yb    = (_Float16*)R;
    _Float16* skiph = Yb + (size_t)N * 256;
    _Float16* qtp   = skiph + (size_t)N * 256;
    _Float16* xaccb = qtp + (size_t)N * 128;
    _Float16* wab   = xaccb + (size_t)N * 256;
    float*    lb    = (float*)(wab + (size_t)N * 128);
    // phase 3 (after gatgemm): e4p over dead Y..skiph..
    _Float16* e4p = (_Float16*)R;
    _Float16* xlh = h16;
    _Float16* xrh = x1h;
    size_t base_off = off;
    _Float16* eap = (_Float16*)alloc((size_t)E * 32 * 2);   // optional 33.5 MB
    int use_eap = (off <= ws_size) ? 1 : 0;

    if (base_off > ws_size) return;   // catastrophic: visible failure

    // weight prep + x fp16
    k_prep<<<512, 256, 0, stream>>>(x, N * 64, wq, wk, wv, wskip, wl, wr,
                                    w1a, w1b, w2a, w2b, we3, bq, we1, we2, we4,
                                    xh, Wts, Gt, Wtl, Wtr,
                                    Wt1a, Wt1b, Wt2a, Wt2b, Mt, cst,
                                    Wt1e, Wt2e, Wt4e, zt, Bt3);

    // edge_index: detect dtype, convert, histogram dst
    k_detect<<<1, 256, 0, stream>>>((const unsigned int*)eidx, flag);
    hipMemsetAsync(counts, 0, (size_t)N * 4, stream);
    k_cvt<<<(2 * E + 255) / 256, 256, 0, stream>>>(eidx, flag, econv, counts, E);
    const int* srcI = econv;
    const int* dstI = econv + E;

    // CSR by dst (pure scatter — no random payload writes)
    k_scan<<<1, 1024, 0, stream>>>(counts, offs, cursor, N);
    k_scatter<<<(E + 255) / 256, 256, 0, stream>>>(dstI, srcI, cursor, perm, sperm, E);

    // e1/e2 materialization: gather-read ea[perm], LDS-coalesced seq writes
    if (use_eap)
        k_emm2<1, 1><<<E / 64, 256, 0, stream>>>(ea, perm, Wt1e, be1, e1p,
                                                 Wt2e, be2, e2p, eap);
    else
        k_emm2<0, 1><<<E / 64, 256, 0, stream>>>(ea, perm, Wt1e, be1, e1p,
                                                 Wt2e, be2, e2p, eap);

    // GINE 1 + MLP1
    k_gine2<<<N / 4, 256, 0, stream>>>(xh, e1p, eps1, offs, sperm, h16);
    k_mlp<64><<<N / 64, 256, 0, stream>>>(h16, Wt1a, b1a, Wt1b, b1b, x1h);

    // GINE 2 + MLP2
    k_gine2<<<N / 4, 256, 0, stream>>>(x1h, e2p, eps2, offs, sperm, h16);
    k_mlp<32><<<N / 64, 256, 0, stream>>>(h16, Wt2a, b2a, Wt2b, b2b, x2h);

    // TransformerConv: Y/skip/qt projections, core, epilogue
    k_gemm4m<<<dim3(N / 64, 9), 256, 0, stream>>>(x2h, Gt, Wts, bskip, Mt, cst,
                                                  Yb, skiph, qtp);
    if (use_eap)
        k_tconv5<1><<<N / 4, 256, 0, stream>>>(Yb, qtp, zt, x2h, eap, ea, perm,
                                               offs, sperm, xaccb, wab, lb);
    else
        k_tconv5<0><<<N / 4, 256, 0, stream>>>(Yb, qtp, zt, x2h, eap, ea, perm,
                                               offs, sperm, xaccb, wab, lb);
    k_tpost<<<N / 64, 256, 0, stream>>>(xaccb, wab, lb, Bt3, bvv, skiph);

    // GATv2: projections (reads skiph), then e4p overlay, then aggregation
    k_gatgemm<<<N / 64, 256, 0, stream>>>(skiph, Wtl, bl, Wtr, br, xlh, xrh);
    if (use_eap)
        k_emm<<<E / 64, 256, 0, stream>>>(eap, Wt4e, (const float*)nullptr, e4p);
    else
        k_emm2<0, 0><<<E / 64, 256, 0, stream>>>(ea, perm, Wt4e,
                                                 (const float*)nullptr, e4p,
                                                 (const _Float16*)nullptr,
                                                 (const float*)nullptr,
                                                 (_Float16*)nullptr,
                                                 (_Float16*)nullptr);
    k_gat2<<<N / 4, 256, 0, stream>>>(xlh, xrh, e4p, attv, bias4, offs, sperm,
                                      (float*)d_out);
}